// Round 6
// baseline (242.469 us; speedup 1.0000x reference)
//
#include <hip/hip_runtime.h>
#include <math.h>

#define LL 8192
#define NLAYERS 4
#define NSTATE 64
#define SQ2H 0.70710678118654752f
#define PI_D 3.14159265358979323846

typedef float v2f __attribute__((ext_vector_type(2)));

// ---- packed fp32 primitives (VOP3P, full-rate on CDNA) ----
// The compiler scalarizes v2f arithmetic (round-5 VALUBusy matched the
// scalar census, not the packed one), so force v_pk_* with inline asm.
__device__ __forceinline__ v2f pk_add(v2f a, v2f b) {
  v2f r; asm("v_pk_add_f32 %0, %1, %2" : "=v"(r) : "v"(a), "v"(b)); return r;
}
__device__ __forceinline__ v2f pk_sub(v2f a, v2f b) {  // a - b
  v2f r; asm("v_pk_add_f32 %0, %1, %2 neg_lo:[0,1] neg_hi:[0,1]" : "=v"(r) : "v"(a), "v"(b)); return r;
}
__device__ __forceinline__ v2f pk_mul(v2f a, v2f b) {
  v2f r; asm("v_pk_mul_f32 %0, %1, %2" : "=v"(r) : "v"(a), "v"(b)); return r;
}
__device__ __forceinline__ v2f pk_fma(v2f a, v2f b, v2f c) {  // a*b + c
  v2f r; asm("v_pk_fma_f32 %0, %1, %2, %3" : "=v"(r) : "v"(a), "v"(b), "v"(c)); return r;
}
__device__ __forceinline__ v2f pk_fms(v2f a, v2f b, v2f c) {  // a*b - c
  v2f r; asm("v_pk_fma_f32 %0, %1, %2, %3 neg_lo:[0,0,1] neg_hi:[0,0,1]" : "=v"(r) : "v"(a), "v"(b), "v"(c)); return r;
}

// packed complex mul (twiddle in registers): r = z * t
#define PCMUL(rx, ry, zx, zy, tx, ty) { \
  rx = pk_fms(zx, tx, pk_mul(zy, ty));  \
  ry = pk_fma(zx, ty, pk_mul(zy, tx)); }
// packed conj mul: r = z * conj(t)
#define PCMULC(rx, ry, zx, zy, tx, ty) { \
  rx = pk_fma(zx, tx, pk_mul(zy, ty));   \
  ry = pk_fms(zy, tx, pk_mul(zx, ty)); }

// C++ complex helpers for CONSTANT twiddles (scalar VOP embeds 32-bit
// literals for free; VOP3P cannot take literals, so packing these would
// cost extra v_mov const materialization).
#define CMULP(rx, ry, zx, zy, tx, ty) { rx = (zx)*(tx) - (zy)*(ty); ry = (zx)*(ty) + (zy)*(tx); }
#define CMULCP(rx, ry, zx, zy, tx, ty) { rx = (zx)*(tx) + (zy)*(ty); ry = (zy)*(tx) - (zx)*(ty); }

// 3 forward DIF stages (sizes 8S,4S,2S), register twiddles -> fully packed
__device__ __forceinline__ void dif3p(v2f X[8], v2f Y[8], v2f t1x, v2f t1y) {
  const v2f sq = {SQ2H, SQ2H};
  v2f t2x = pk_fms(t1x, t1x, pk_mul(t1y, t1y));
  v2f tp  = pk_mul(t1x, t1y);
  v2f t2y = pk_add(tp, tp);
  v2f t4x = pk_fms(t2x, t2x, pk_mul(t2y, t2y));
  v2f tq  = pk_mul(t2x, t2y);
  v2f t4y = pk_add(tq, tq);
#pragma unroll
  for (int k = 0; k < 4; k++) {          // m=8S: (k,k+4), tw = C8[k]*t1
    v2f ax = X[k], ay = Y[k], bx = X[k+4], by = Y[k+4];
    X[k] = pk_add(ax, bx); Y[k] = pk_add(ay, by);
    v2f dx = pk_sub(ax, bx), dy = pk_sub(ay, by), ex, ey;
    if (k == 0)      { ex = dx; ey = dy; }
    else if (k == 1) { ex = pk_mul(pk_add(dx, dy), sq); ey = pk_mul(pk_sub(dy, dx), sq); }
    else if (k == 2) { ex = dy; ey = -dx; }
    else             { ex = pk_mul(pk_sub(dy, dx), sq); ey = -pk_mul(pk_add(dx, dy), sq); }
    PCMUL(X[k+4], Y[k+4], ex, ey, t1x, t1y);
  }
#pragma unroll
  for (int h = 0; h < 8; h += 4)         // m=4S: (k,k+2), tw = t2*{1,-i}
#pragma unroll
    for (int l = 0; l < 2; l++) {
      int k = h + l;
      v2f ax = X[k], ay = Y[k], bx = X[k+2], by = Y[k+2];
      X[k] = pk_add(ax, bx); Y[k] = pk_add(ay, by);
      v2f dx = pk_sub(ax, bx), dy = pk_sub(ay, by), ex, ey;
      PCMUL(ex, ey, dx, dy, t2x, t2y);
      if (l == 0) { X[k+2] = ex; Y[k+2] = ey; }
      else        { X[k+2] = ey; Y[k+2] = -ex; }   // * -i
    }
#pragma unroll
  for (int k = 0; k < 8; k += 2) {       // m=2S: (k,k+1), tw = t4
    v2f ax = X[k], ay = Y[k], bx = X[k+1], by = Y[k+1];
    X[k] = pk_add(ax, bx); Y[k] = pk_add(ay, by);
    v2f dx = pk_sub(ax, bx), dy = pk_sub(ay, by);
    PCMUL(X[k+1], Y[k+1], dx, dy, t4x, t4y);
  }
}

// 3 inverse DIT stages, register twiddles -> fully packed
__device__ __forceinline__ void dit3p(v2f X[8], v2f Y[8], v2f t1x, v2f t1y) {
  const v2f sq = {SQ2H, SQ2H};
  v2f t2x = pk_fms(t1x, t1x, pk_mul(t1y, t1y));
  v2f tp  = pk_mul(t1x, t1y);
  v2f t2y = pk_add(tp, tp);
  v2f t4x = pk_fms(t2x, t2x, pk_mul(t2y, t2y));
  v2f tq  = pk_mul(t2x, t2y);
  v2f t4y = pk_add(tq, tq);
#pragma unroll
  for (int k = 0; k < 8; k += 2) {       // m1: (k,k+1), b *= conj(t4)
    v2f bx, by;
    PCMULC(bx, by, X[k+1], Y[k+1], t4x, t4y);
    v2f ax = X[k], ay = Y[k];
    X[k]   = pk_add(ax, bx); Y[k]   = pk_add(ay, by);
    X[k+1] = pk_sub(ax, bx); Y[k+1] = pk_sub(ay, by);
  }
#pragma unroll
  for (int h = 0; h < 8; h += 4)         // 2m1: (k,k+2), b *= conj(t2)*{1,+i}
#pragma unroll
    for (int l = 0; l < 2; l++) {
      int k = h + l;
      v2f bx, by;
      PCMULC(bx, by, X[k+2], Y[k+2], t2x, t2y);
      if (l == 1) { v2f tm = bx; bx = -by; by = tm; }  // * +i
      v2f ax = X[k], ay = Y[k];
      X[k]   = pk_add(ax, bx); Y[k]   = pk_add(ay, by);
      X[k+2] = pk_sub(ax, bx); Y[k+2] = pk_sub(ay, by);
    }
#pragma unroll
  for (int k = 0; k < 4; k++) {          // 4m1: (k,k+4), b = conj(C8[k])*conj(t1)*b
    v2f cx, cy;
    PCMULC(cx, cy, X[k+4], Y[k+4], t1x, t1y);
    v2f bx, by;
    if (k == 0)      { bx = cx; by = cy; }
    else if (k == 1) { bx = pk_mul(pk_sub(cx, cy), sq); by = pk_mul(pk_add(cx, cy), sq); }
    else if (k == 2) { bx = -cy; by = cx; }
    else             { bx = -pk_mul(pk_add(cx, cy), sq); by = pk_mul(pk_sub(cx, cy), sq); }
    v2f ax = X[k], ay = Y[k];
    X[k]   = pk_add(ax, bx); Y[k]   = pk_add(ay, by);
    X[k+4] = pk_sub(ax, bx); Y[k+4] = pk_sub(ay, by);
  }
}

// forward stages m=16,8,4,2: const twiddles stay scalar (free literals),
// data-data butterflies packed.
__device__ __forceinline__ void fwd4p(v2f X[8], v2f Y[8]) {
  const float c16[8] = {1.f, 0.92387953f, 0.70710678f, 0.38268343f,
                        0.f, -0.38268343f, -0.70710678f, -0.92387953f};
  const float s16[8] = {0.f, -0.38268343f, -0.70710678f, -0.92387953f,
                        -1.f, -0.92387953f, -0.70710678f, -0.38268343f};
#pragma unroll
  for (int k = 0; k < 4; k++) {          // m=16: (k,k+4), tw = W16^{2k+lane}
    v2f tx = {c16[2*k], c16[2*k+1]}, ty = {s16[2*k], s16[2*k+1]};
    v2f ax = X[k], ay = Y[k], bx = X[k+4], by = Y[k+4];
    X[k] = pk_add(ax, bx); Y[k] = pk_add(ay, by);
    v2f dx = pk_sub(ax, bx), dy = pk_sub(ay, by);
    CMULP(X[k+4], Y[k+4], dx, dy, tx, ty);
  }
#pragma unroll
  for (int h = 0; h < 8; h += 4)         // m=8: (k,k+2), tw = W8^{2l+lane}
#pragma unroll
    for (int l = 0; l < 2; l++) {
      int k = h + l;
      v2f tx = (l == 0) ? v2f{1.f, SQ2H} : v2f{0.f, -SQ2H};
      v2f ty = (l == 0) ? v2f{0.f, -SQ2H} : v2f{-1.f, -SQ2H};
      v2f ax = X[k], ay = Y[k], bx = X[k+2], by = Y[k+2];
      X[k] = pk_add(ax, bx); Y[k] = pk_add(ay, by);
      v2f dx = pk_sub(ax, bx), dy = pk_sub(ay, by);
      CMULP(X[k+2], Y[k+2], dx, dy, tx, ty);
    }
#pragma unroll
  for (int k = 0; k < 8; k += 2) {       // m=4: (k,k+1), tw = {1,-i} per lane
    v2f ax = X[k], ay = Y[k], bx = X[k+1], by = Y[k+1];
    X[k] = pk_add(ax, bx); Y[k] = pk_add(ay, by);
    v2f dx = pk_sub(ax, bx), dy = pk_sub(ay, by);
    X[k+1] = v2f{dx.x, dy.y};
    Y[k+1] = v2f{dy.x, -dx.y};
  }
#pragma unroll
  for (int u = 0; u < 8; u++) {          // m=2: cross-lane (horizontal, scalar)
    v2f x = X[u], y = Y[u];
    X[u] = v2f{x.x + x.y, x.x - x.y};
    Y[u] = v2f{y.x + y.y, y.x - y.y};
  }
}

// inverse stages m=2,4,8,16
__device__ __forceinline__ void inv4p(v2f X[8], v2f Y[8]) {
  const float c16[8] = {1.f, 0.92387953f, 0.70710678f, 0.38268343f,
                        0.f, -0.38268343f, -0.70710678f, -0.92387953f};
  const float s16[8] = {0.f, -0.38268343f, -0.70710678f, -0.92387953f,
                        -1.f, -0.92387953f, -0.70710678f, -0.38268343f};
#pragma unroll
  for (int u = 0; u < 8; u++) {          // m=2: cross-lane (horizontal, scalar)
    v2f x = X[u], y = Y[u];
    X[u] = v2f{x.x + x.y, x.x - x.y};
    Y[u] = v2f{y.x + y.y, y.x - y.y};
  }
#pragma unroll
  for (int k = 0; k < 8; k += 2) {       // m=4: (k,k+1), b *= {1,+i} per lane
    v2f bx0 = X[k+1], by0 = Y[k+1];
    v2f bx = v2f{bx0.x, -by0.y};
    v2f by = v2f{by0.x, bx0.y};
    v2f ax = X[k], ay = Y[k];
    X[k]   = pk_add(ax, bx); Y[k]   = pk_add(ay, by);
    X[k+1] = pk_sub(ax, bx); Y[k+1] = pk_sub(ay, by);
  }
#pragma unroll
  for (int h = 0; h < 8; h += 4)         // m=8: (k,k+2), b *= conj(W8^{2l+lane})
#pragma unroll
    for (int l = 0; l < 2; l++) {
      int k = h + l;
      v2f tx = (l == 0) ? v2f{1.f, SQ2H} : v2f{0.f, -SQ2H};
      v2f ty = (l == 0) ? v2f{0.f, -SQ2H} : v2f{-1.f, -SQ2H};
      v2f bx, by;
      CMULCP(bx, by, X[k+2], Y[k+2], tx, ty);
      v2f ax = X[k], ay = Y[k];
      X[k]   = pk_add(ax, bx); Y[k]   = pk_add(ay, by);
      X[k+2] = pk_sub(ax, bx); Y[k+2] = pk_sub(ay, by);
    }
#pragma unroll
  for (int k = 0; k < 4; k++) {          // m=16: (k,k+4), b *= conj(W16^{2k+lane})
    v2f tx = {c16[2*k], c16[2*k+1]}, ty = {s16[2*k], s16[2*k+1]};
    v2f bx, by;
    CMULCP(bx, by, X[k+4], Y[k+4], tx, ty);
    v2f ax = X[k], ay = Y[k];
    X[k]   = pk_add(ax, bx); Y[k]   = pk_add(ay, by);
    X[k+4] = pk_sub(ax, bx); Y[k+4] = pk_sub(ay, by);
  }
}

// Branch-free GELU: erf via Abramowitz-Stegun 7.1.26 (|err| <= 1.5e-7).
// Replaces libm erff (divergent branch + global coefficient-table fetches:
// removing it cut FETCH_SIZE 155MB -> 70MB and dur 348 -> 243us in round 5).
__device__ __forceinline__ float gelu_fast(float x) {
  const float z = x * 0.70710678118654752f;       // x / sqrt(2)
  const float a = fabsf(z);
  const float t = __builtin_amdgcn_rcpf(fmaf(0.3275911f, a, 1.0f));
  float p = fmaf(1.061405429f, t, -1.453152027f);
  p = fmaf(p, t, 1.421413741f);
  p = fmaf(p, t, -0.284496736f);
  p = fmaf(p, t, 0.254829592f);
  p = p * t;
  const float e = __builtin_amdgcn_exp2f(-a * (a * 1.4426950408889634f)); // exp(-a^2)
  float erfa = fmaf(-p, e, 1.0f);                 // erf(|z|)
  erfa = copysignf(erfa, z);
  return 0.5f * x * (1.0f + erfa);
}

// ---- LDS exchanges, full float4 width (b128) ----
// Occupancy is VGPR-capped at 2 blocks/CU (64 VGPR -> 4 waves/SIMD), so the
// 73.7KB float4 buffer costs nothing, while minimizing barrier and issue-slot
// count. LDS pipe time is bytes-bound (b64 vs b128 throughput-neutral, r3 vs r4).
// Buffer is 8 disjoint 576-unit slices, one per wave (threads 64w..64w+63):
// b2/b3/b4 layouts index strictly within slice [576w, 576w+576); only the b1
// layout (stride-576 across the block) crosses slices.

#define ST4(idx, k) lds[idx] = make_float4(X[k].x, X[k].y, Y[k].x, Y[k].y)
#define LD4(idx, k) { float4 q = lds[idx]; X[k] = v2f{q.x, q.y}; Y[k] = v2f{q.z, q.w}; }

// F1 exchange: write b1 (cross-slice), read b2 (own slice).
// Leading barrier = WAR vs previous layer's cross-slice I3 reads of b1.
// Middle barrier = RAW (other waves' writes land in my slice).
__device__ __forceinline__ void xchg_f1(v2f X[8], v2f Y[8], float4* lds,
                                        int wb, int rb) {
  __syncthreads();
#pragma unroll
  for (int k = 0; k < 8; k++) ST4(wb + 576*k, k);
  __syncthreads();
#pragma unroll
  for (int k = 0; k < 8; k++) LD4(rb + 72*k, k);
}

// I3 exchange: write b2 (own slice - WAR covered by in-wave ordering vs my own
// I2 reads), read b1 (cross-slice - one RAW barrier).
__device__ __forceinline__ void xchg_i3(v2f X[8], v2f Y[8], float4* lds,
                                        int wb, int rb) {
#pragma unroll
  for (int k = 0; k < 8; k++) ST4(wb + 72*k, k);
  __syncthreads();
#pragma unroll
  for (int k = 0; k < 8; k++) LD4(rb + 576*k, k);
}

// Intra-wave exchange: both layouts inside this wave's private slice.
// NO barriers: same-wave DS ops are processed in order; compiler lgkmcnt
// waits cover the RAW edges. Waves drift freely past each other here.
__device__ __forceinline__ void xchg_wav(v2f X[8], v2f Y[8], float4* lds,
                                         int wb, int ws, int rb, int rs) {
#pragma unroll
  for (int k = 0; k < 8; k++) ST4(wb + ws*k, k);
#pragma unroll
  for (int k = 0; k < 8; k++) LD4(rb + rs*k, k);
}

// ---- setup: khp float4 units (re_e, re_o, im_e, im_o), bins in bitrev13 order,
// value = (Kh(f)+1)/L ; each thread computes f in [0,4096] and writes f and L-f (conj)
__global__ void ssm_setup(const float* __restrict__ Lr, const float* __restrict__ Li,
                          const float* __restrict__ Pv, const float* __restrict__ Bv,
                          const float* __restrict__ Cv, const float* __restrict__ Sv,
                          float* __restrict__ khp) {
  const int f = blockIdx.x * blockDim.x + threadIdx.x;
  const int layer = blockIdx.y;
  if (f > LL/2) return;
  const double step = (double)Sv[layer];
  const float* lr = Lr + layer * NSTATE;
  const float* li = Li + layer * NSTATE;
  const float* pp = Pv + layer * NSTATE;
  const float* bb = Bv + layer * NSTATE;
  const float* ct = Cv + layer * NSTATE;
  const double ts = 2.0 / step;

  double Kr[2], Ki[2];
  const int f2[2] = { f, (LL - f) & (LL - 1) };
#pragma unroll 1
  for (int s = 0; s < 2; s++) {
    const double th = -2.0 * PI_D * (double)f2[s] / (double)LL;
    const double co = cos(th), si = sin(th);
    const double pr = 1.0 + co, pim = si;
    const double pd = pr*pr + pim*pim;
    const double rpd = 1.0 / pd;
    const double cr = 2.0*pr*rpd, ci = -2.0*pim*rpd;        // c = 2/(1+Om)
    const double mr = 1.0 - co, mi = -si;
    const double gr = ts*(mr*pr + mi*pim)*rpd;              // g = ts*(1-Om)/(1+Om)
    const double gi = ts*(mi*pr - mr*pim)*rpd;
    double k00r=0,k00i=0,k01r=0,k01i=0,k10r=0,k10i=0,k11r=0,k11i=0;
    for (int n = 0; n < NSTATE; n++) {
      const double dr = gr - (double)lr[n];
      const double di = gi - (double)li[n];
      const double rd = 1.0 / (dr*dr + di*di);
      const double ir = dr*rd, ii = -di*rd;                 // 1/denom
      const double p = (double)pp[n], b = (double)bb[n], c = (double)ct[n];
      double w;
      w = c*b; k00r += w*ir; k00i += w*ii;
      w = c*p; k01r += w*ir; k01i += w*ii;
      w = p*b; k10r += w*ir; k10i += w*ii;
      w = p*p; k11r += w*ir; k11i += w*ii;
    }
    const double ar = k01r*k10r - k01i*k10i;
    const double ai = k01r*k10i + k01i*k10r;
    const double qr = 1.0 + k11r, qi = k11i;
    const double rqd = 1.0 / (qr*qr + qi*qi);
    const double br = (ar*qr + ai*qi)*rqd, bi = (ai*qr - ar*qi)*rqd;
    const double sr = k00r - br, sj = k00i - bi;
    Kr[s] = cr*sr - ci*sj;
    Ki[s] = cr*sj + ci*sr;
  }
  const double hr = 0.5*(Kr[0] + Kr[1]);                    // Hermitian part
  const double hi = 0.5*(Ki[0] - Ki[1]);
  const double invL = 1.0 / (double)LL;
  const float re = (float)((hr + 1.0)*invL);
  const float im = (float)(hi*invL);
  const int i0 = (int)(__brev((unsigned)f) >> 19);
  const int i1 = (int)(__brev((unsigned)f2[1]) >> 19);
  float* kl = khp + layer * (LL * 2);                       // 16384 floats per layer
  kl[(i0 >> 1)*4 + (i0 & 1)]     = re;                      // bin f
  kl[(i0 >> 1)*4 + 2 + (i0 & 1)] = im;
  kl[(i1 >> 1)*4 + (i1 & 1)]     = re;                      // bin L-f = conj
  kl[(i1 >> 1)*4 + 2 + (i1 & 1)] = -im;
}

// ---- fused 4-layer SSM, packed-fp32 layout:
// unit u holds complex elements (2u, 2u+1); X = re pair, Y = im pair.
// __launch_bounds__(512,4): allocator lands at exactly 64 VGPR (budget 256/4);
// (512,8) caps at 32 VGPR -> catastrophic scratch spilling. Effective VGPR
// pool is ~256/SIMD: at 64 VGPR we get 4 waves/SIMD = 2 blocks/CU.
__global__ __launch_bounds__(512, 4) void ssm_fused(const float* __restrict__ uin,
                                                    const float* __restrict__ khp,
                                                    float* __restrict__ uout) {
  __shared__ float4 lds[4607];   // 4096 float4 units (+1 pad per 8) = 73,712 B
  const int t = threadIdx.x;
  const size_t rb = (size_t)blockIdx.x * (2 * LL);
  const v2f* p0 = (const v2f*)(uin + rb);
  const v2f* p1 = (const v2f*)(uin + rb + LL);

  v2f X[8], Y[8];                // unit index t + 512k
#pragma unroll
  for (int k = 0; k < 8; k++) {
    X[k] = p0[t + 512*k];
    Y[k] = p1[t + 512*k];
  }

  v2f e13x, e13y, e10x, e10y, e7x, e7y;
  {
    const float w13 = -(float)(2.0 * PI_D / 8192.0);
    const float w10 = -(float)(2.0 * PI_D / 1024.0);
    const float w7  = -(float)(2.0 * PI_D / 128.0);
    float c0, s0, c1, s1, r;
    r = (float)(2*t);       sincosf(w13*r, &s0, &c0); sincosf(w13*(r+1.0f), &s1, &c1);
    e13x = v2f{c0, c1}; e13y = v2f{s0, s1};
    r = (float)(2*(t&63));  sincosf(w10*r, &s0, &c0); sincosf(w10*(r+1.0f), &s1, &c1);
    e10x = v2f{c0, c1}; e10y = v2f{s0, s1};
    r = (float)(2*(t&7));   sincosf(w7*r, &s0, &c0);  sincosf(w7*(r+1.0f), &s1, &c1);
    e7x = v2f{c0, c1};  e7y = v2f{s0, s1};
  }

  const int m6 = t & 63;
  const int b1 = t + (t >> 3);                  // {t + 512k} units, stride 576 (cross-slice)
  const int b2 = 576*(t >> 6) + m6 + (m6 >> 3); // {512g + m + 64k}, stride 72 (own slice)
  const int b3 = 72*(t >> 3) + (t & 7);         // {64g + s + 8k}, stride 9 (own slice)
  const int b4 = 9*t;                           // {8t + j}, stride 1 (own slice)

  const float4* kb = (const float4*)khp;

#pragma unroll 1
  for (int layer = 0; layer < NLAYERS; layer++) {
    // F1: DIF m=8192,4096,2048
    dif3p(X, Y, e13x, e13y);
    xchg_f1(X, Y, lds, b1, b2);                 // block-wide (2 barriers)
    // F2: m=1024,512,256
    dif3p(X, Y, e10x, e10y);
    xchg_wav(X, Y, lds, b2, 72, b3, 9);         // intra-wave, no barrier
    // F3: m=128,64,32
    dif3p(X, Y, e7x, e7y);
    xchg_wav(X, Y, lds, b3, 9, b4, 1);          // intra-wave, no barrier
    // F45 + pointwise (bit-reversed) + I1
    {
      float4 kq[8];
      const float4* kv = kb + (layer << 12) + 8*t;
#pragma unroll
      for (int k = 0; k < 8; k++) kq[k] = kv[k];
      fwd4p(X, Y);
#pragma unroll
      for (int k = 0; k < 8; k++) {
        v2f kx = {kq[k].x, kq[k].y}, ky = {kq[k].z, kq[k].w};
        v2f nx, ny;
        PCMUL(nx, ny, X[k], Y[k], kx, ky);
        X[k] = nx; Y[k] = ny;
      }
      inv4p(X, Y);
    }
    xchg_wav(X, Y, lds, b4, 1, b3, 9);          // intra-wave, no barrier
    // I2: m=32,64,128
    dit3p(X, Y, e7x, e7y);
    xchg_wav(X, Y, lds, b3, 9, b2, 72);         // intra-wave, no barrier
    // I3: m=256,512,1024
    dit3p(X, Y, e10x, e10y);
    xchg_i3(X, Y, lds, b2, b1);                 // block-wide (1 barrier)
    // I4: m=2048,4096,8192, then GELU (1/L folded into khp)
    dit3p(X, Y, e13x, e13y);
#pragma unroll
    for (int k = 0; k < 8; k++) {
      X[k].x = gelu_fast(X[k].x); X[k].y = gelu_fast(X[k].y);
      Y[k].x = gelu_fast(Y[k].x); Y[k].y = gelu_fast(Y[k].y);
    }
  }

  v2f* o0 = (v2f*)(uout + rb);
  v2f* o1 = (v2f*)(uout + rb + LL);
#pragma unroll
  for (int k = 0; k < 8; k++) {
    o0[t + 512*k] = X[k];
    o1[t + 512*k] = Y[k];
  }
}

extern "C" void kernel_launch(void* const* d_in, const int* in_sizes, int n_in,
                              void* d_out, int out_size, void* d_ws, size_t ws_size,
                              hipStream_t stream) {
  const float* u  = (const float*)d_in[0];
  const float* Lr = (const float*)d_in[1];
  const float* Li = (const float*)d_in[2];
  const float* P  = (const float*)d_in[3];
  const float* B  = (const float*)d_in[4];
  const float* C  = (const float*)d_in[5];
  const float* S  = (const float*)d_in[6];
  float* khp = (float*)d_ws;  // 4 layers * 16384 floats = 256 KB

  hipLaunchKernelGGL(ssm_setup, dim3((LL/2 + 256) / 256, NLAYERS), dim3(256), 0, stream,
                     Lr, Li, P, B, C, S, khp);
  hipLaunchKernelGGL(ssm_fused, dim3(4096/2), dim3(512), 0, stream,
                     u, khp, (float*)d_out);
}

// Round 7
// 238.271 us; speedup vs baseline: 1.0176x; 1.0176x over previous
//
#include <hip/hip_runtime.h>
#include <math.h>

#define LL 8192
#define NLAYERS 4
#define NSTATE 64
#define SQ2H 0.70710678118654752f
#define PI_D 3.14159265358979323846

typedef float v2f __attribute__((ext_vector_type(2)));

// packed complex helpers: (X,Y) = (re-pair, im-pair), twiddle (tx,ty)
// NOTE: plain C++ v2f arithmetic. Round 6 proved v_pk_*_f32 is RATE-NEUTRAL
// on gfx950 (fp32 peak == scalar issue rate; VOP3P takes 2 ops' pipe time),
// and inline-asm packing only hurt scheduling (-3%). Let the compiler choose.
#define CMULP(rx, ry, zx, zy, tx, ty) { rx = (zx)*(tx) - (zy)*(ty); ry = (zx)*(ty) + (zy)*(tx); }
#define CMULCP(rx, ry, zx, zy, tx, ty) { rx = (zx)*(tx) + (zy)*(ty); ry = (zy)*(tx) - (zx)*(ty); }

#define LD4(idx, k) { float4 q = lds[idx]; X[k] = v2f{q.x, q.y}; Y[k] = v2f{q.z, q.w}; }
#define ST4(idx, k) lds[idx] = make_float4(X[k].x, X[k].y, Y[k].x, Y[k].y)

// 3 forward DIF stages (sizes 8S,4S,2S), data already in registers (F1 only)
__device__ __forceinline__ void dif3p(v2f X[8], v2f Y[8], v2f t1x, v2f t1y) {
  v2f t2x = t1x*t1x - t1y*t1y, t2y = 2.0f*(t1x*t1y);
  v2f t4x = t2x*t2x - t2y*t2y, t4y = 2.0f*(t2x*t2y);
#pragma unroll
  for (int k = 0; k < 4; k++) {          // m=8S: (k,k+4), tw = C8[k]*t1
    v2f ax = X[k], ay = Y[k], bx = X[k+4], by = Y[k+4];
    X[k] = ax + bx; Y[k] = ay + by;
    v2f dx = ax - bx, dy = ay - by, ex, ey;
    if (k == 0)      { ex = dx; ey = dy; }
    else if (k == 1) { ex = (dx + dy) * SQ2H; ey = (dy - dx) * SQ2H; }
    else if (k == 2) { ex = dy; ey = -dx; }
    else             { ex = (dy - dx) * SQ2H; ey = -((dx + dy) * SQ2H); }
    CMULP(X[k+4], Y[k+4], ex, ey, t1x, t1y);
  }
#pragma unroll
  for (int h = 0; h < 8; h += 4)         // m=4S: (k,k+2), tw = t2*{1,-i}
#pragma unroll
    for (int l = 0; l < 2; l++) {
      int k = h + l;
      v2f ax = X[k], ay = Y[k], bx = X[k+2], by = Y[k+2];
      X[k] = ax + bx; Y[k] = ay + by;
      v2f dx = ax - bx, dy = ay - by, ex, ey;
      CMULP(ex, ey, dx, dy, t2x, t2y);
      if (l == 0) { X[k+2] = ex; Y[k+2] = ey; }
      else        { X[k+2] = ey; Y[k+2] = -ex; }   // * -i
    }
#pragma unroll
  for (int k = 0; k < 8; k += 2) {       // m=2S: (k,k+1), tw = t4
    v2f ax = X[k], ay = Y[k], bx = X[k+1], by = Y[k+1];
    X[k] = ax + bx; Y[k] = ay + by;
    v2f dx = ax - bx, dy = ay - by;
    CMULP(X[k+1], Y[k+1], dx, dy, t4x, t4y);
  }
}

// Fused LDS-read + 3 forward DIF stages: reads are issued in butterfly-pair
// order (k, k+4) and each stage-1 butterfly sits right after its own loads,
// so compute starts after 2 LDS returns (lgkmcnt(6)) instead of all 8.
__device__ __forceinline__ void ld_dif3p(v2f X[8], v2f Y[8], const float4* lds,
                                         int rb, int rs, v2f t1x, v2f t1y) {
  v2f t2x = t1x*t1x - t1y*t1y, t2y = 2.0f*(t1x*t1y);
  v2f t4x = t2x*t2x - t2y*t2y, t4y = 2.0f*(t2x*t2y);
#pragma unroll
  for (int k = 0; k < 4; k++) {          // m=8S: (k,k+4), tw = C8[k]*t1
    LD4(rb + rs*k, k);
    LD4(rb + rs*(k+4), k+4);
    v2f ax = X[k], ay = Y[k], bx = X[k+4], by = Y[k+4];
    X[k] = ax + bx; Y[k] = ay + by;
    v2f dx = ax - bx, dy = ay - by, ex, ey;
    if (k == 0)      { ex = dx; ey = dy; }
    else if (k == 1) { ex = (dx + dy) * SQ2H; ey = (dy - dx) * SQ2H; }
    else if (k == 2) { ex = dy; ey = -dx; }
    else             { ex = (dy - dx) * SQ2H; ey = -((dx + dy) * SQ2H); }
    CMULP(X[k+4], Y[k+4], ex, ey, t1x, t1y);
  }
#pragma unroll
  for (int h = 0; h < 8; h += 4)         // m=4S
#pragma unroll
    for (int l = 0; l < 2; l++) {
      int k = h + l;
      v2f ax = X[k], ay = Y[k], bx = X[k+2], by = Y[k+2];
      X[k] = ax + bx; Y[k] = ay + by;
      v2f dx = ax - bx, dy = ay - by, ex, ey;
      CMULP(ex, ey, dx, dy, t2x, t2y);
      if (l == 0) { X[k+2] = ex; Y[k+2] = ey; }
      else        { X[k+2] = ey; Y[k+2] = -ex; }
    }
#pragma unroll
  for (int k = 0; k < 8; k += 2) {       // m=2S
    v2f ax = X[k], ay = Y[k], bx = X[k+1], by = Y[k+1];
    X[k] = ax + bx; Y[k] = ay + by;
    v2f dx = ax - bx, dy = ay - by;
    CMULP(X[k+1], Y[k+1], dx, dy, t4x, t4y);
  }
}

// Fused LDS-read + 3 inverse DIT stages: stage-1 pairs are (k,k+1) — loads
// for each pair immediately precede its butterfly.
__device__ __forceinline__ void ld_dit3p(v2f X[8], v2f Y[8], const float4* lds,
                                         int rb, int rs, v2f t1x, v2f t1y) {
  v2f t2x = t1x*t1x - t1y*t1y, t2y = 2.0f*(t1x*t1y);
  v2f t4x = t2x*t2x - t2y*t2y, t4y = 2.0f*(t2x*t2y);
#pragma unroll
  for (int k = 0; k < 8; k += 2) {       // m1: (k,k+1), b *= conj(t4)
    LD4(rb + rs*k, k);
    LD4(rb + rs*(k+1), k+1);
    v2f bx, by;
    CMULCP(bx, by, X[k+1], Y[k+1], t4x, t4y);
    v2f ax = X[k], ay = Y[k];
    X[k] = ax + bx;   Y[k] = ay + by;
    X[k+1] = ax - bx; Y[k+1] = ay - by;
  }
#pragma unroll
  for (int h = 0; h < 8; h += 4)         // 2m1: (k,k+2), b *= conj(t2)*{1,+i}
#pragma unroll
    for (int l = 0; l < 2; l++) {
      int k = h + l;
      v2f bx, by;
      CMULCP(bx, by, X[k+2], Y[k+2], t2x, t2y);
      if (l == 1) { v2f tm = bx; bx = -by; by = tm; }  // * +i
      v2f ax = X[k], ay = Y[k];
      X[k] = ax + bx;   Y[k] = ay + by;
      X[k+2] = ax - bx; Y[k+2] = ay - by;
    }
#pragma unroll
  for (int k = 0; k < 4; k++) {          // 4m1: (k,k+4), b = conj(C8[k])*conj(t1)*b
    v2f cx, cy;
    CMULCP(cx, cy, X[k+4], Y[k+4], t1x, t1y);
    v2f bx, by;
    if (k == 0)      { bx = cx; by = cy; }
    else if (k == 1) { bx = (cx - cy) * SQ2H; by = (cx + cy) * SQ2H; }
    else if (k == 2) { bx = -cy; by = cx; }
    else             { bx = -((cx + cy) * SQ2H); by = (cx - cy) * SQ2H; }
    v2f ax = X[k], ay = Y[k];
    X[k] = ax + bx;   Y[k] = ay + by;
    X[k+4] = ax - bx; Y[k+4] = ay - by;
  }
}

// Fused LDS-read (stride 1) + forward stages m=16,8,4,2
__device__ __forceinline__ void ld_fwd4p(v2f X[8], v2f Y[8], const float4* lds,
                                         int rb) {
  const float c16[8] = {1.f, 0.92387953f, 0.70710678f, 0.38268343f,
                        0.f, -0.38268343f, -0.70710678f, -0.92387953f};
  const float s16[8] = {0.f, -0.38268343f, -0.70710678f, -0.92387953f,
                        -1.f, -0.92387953f, -0.70710678f, -0.38268343f};
#pragma unroll
  for (int k = 0; k < 4; k++) {          // m=16: (k,k+4), tw = W16^{2k+lane}
    LD4(rb + k, k);
    LD4(rb + k + 4, k+4);
    v2f tx = {c16[2*k], c16[2*k+1]}, ty = {s16[2*k], s16[2*k+1]};
    v2f ax = X[k], ay = Y[k], bx = X[k+4], by = Y[k+4];
    X[k] = ax + bx; Y[k] = ay + by;
    v2f dx = ax - bx, dy = ay - by;
    CMULP(X[k+4], Y[k+4], dx, dy, tx, ty);
  }
#pragma unroll
  for (int h = 0; h < 8; h += 4)         // m=8: (k,k+2), tw = W8^{2l+lane}
#pragma unroll
    for (int l = 0; l < 2; l++) {
      int k = h + l;
      v2f tx = (l == 0) ? v2f{1.f, SQ2H} : v2f{0.f, -SQ2H};
      v2f ty = (l == 0) ? v2f{0.f, -SQ2H} : v2f{-1.f, -SQ2H};
      v2f ax = X[k], ay = Y[k], bx = X[k+2], by = Y[k+2];
      X[k] = ax + bx; Y[k] = ay + by;
      v2f dx = ax - bx, dy = ay - by;
      CMULP(X[k+2], Y[k+2], dx, dy, tx, ty);
    }
#pragma unroll
  for (int k = 0; k < 8; k += 2) {       // m=4: (k,k+1), tw = {1,-i} per lane
    v2f ax = X[k], ay = Y[k], bx = X[k+1], by = Y[k+1];
    X[k] = ax + bx; Y[k] = ay + by;
    v2f dx = ax - bx, dy = ay - by;
    X[k+1] = v2f{dx.x, dy.y};
    Y[k+1] = v2f{dy.x, -dx.y};
  }
#pragma unroll
  for (int u = 0; u < 8; u++) {          // m=2: cross-lane
    v2f x = X[u], y = Y[u];
    X[u] = v2f{x.x + x.y, x.x - x.y};
    Y[u] = v2f{y.x + y.y, y.x - y.y};
  }
}

// inverse stages m=2,4,8,16 (data in registers)
__device__ __forceinline__ void inv4p(v2f X[8], v2f Y[8]) {
  const float c16[8] = {1.f, 0.92387953f, 0.70710678f, 0.38268343f,
                        0.f, -0.38268343f, -0.70710678f, -0.92387953f};
  const float s16[8] = {0.f, -0.38268343f, -0.70710678f, -0.92387953f,
                        -1.f, -0.92387953f, -0.70710678f, -0.38268343f};
#pragma unroll
  for (int u = 0; u < 8; u++) {          // m=2: cross-lane
    v2f x = X[u], y = Y[u];
    X[u] = v2f{x.x + x.y, x.x - x.y};
    Y[u] = v2f{y.x + y.y, y.x - y.y};
  }
#pragma unroll
  for (int k = 0; k < 8; k += 2) {       // m=4: (k,k+1), b *= {1,+i} per lane
    v2f bx0 = X[k+1], by0 = Y[k+1];
    v2f bx = v2f{bx0.x, -by0.y};
    v2f by = v2f{by0.x, bx0.y};
    v2f ax = X[k], ay = Y[k];
    X[k] = ax + bx;   Y[k] = ay + by;
    X[k+1] = ax - bx; Y[k+1] = ay - by;
  }
#pragma unroll
  for (int h = 0; h < 8; h += 4)         // m=8: (k,k+2), b *= conj(W8^{2l+lane})
#pragma unroll
    for (int l = 0; l < 2; l++) {
      int k = h + l;
      v2f tx = (l == 0) ? v2f{1.f, SQ2H} : v2f{0.f, -SQ2H};
      v2f ty = (l == 0) ? v2f{0.f, -SQ2H} : v2f{-1.f, -SQ2H};
      v2f bx, by;
      CMULCP(bx, by, X[k+2], Y[k+2], tx, ty);
      v2f ax = X[k], ay = Y[k];
      X[k] = ax + bx;   Y[k] = ay + by;
      X[k+2] = ax - bx; Y[k+2] = ay - by;
    }
#pragma unroll
  for (int k = 0; k < 4; k++) {          // m=16: (k,k+4), b *= conj(W16^{2k+lane})
    v2f tx = {c16[2*k], c16[2*k+1]}, ty = {s16[2*k], s16[2*k+1]};
    v2f bx, by;
    CMULCP(bx, by, X[k+4], Y[k+4], tx, ty);
    v2f ax = X[k], ay = Y[k];
    X[k] = ax + bx;   Y[k] = ay + by;
    X[k+4] = ax - bx; Y[k+4] = ay - by;
  }
}

// Branch-free GELU: erf via Abramowitz-Stegun 7.1.26 (|err| <= 1.5e-7).
// Replaces libm erff (divergent branch + global coefficient-table fetches:
// removing it cut FETCH_SIZE 155MB -> 70MB and dur 348 -> 243us in round 5).
__device__ __forceinline__ float gelu_fast(float x) {
  const float z = x * 0.70710678118654752f;       // x / sqrt(2)
  const float a = fabsf(z);
  const float t = __builtin_amdgcn_rcpf(fmaf(0.3275911f, a, 1.0f));
  float p = fmaf(1.061405429f, t, -1.453152027f);
  p = fmaf(p, t, 1.421413741f);
  p = fmaf(p, t, -0.284496736f);
  p = fmaf(p, t, 0.254829592f);
  p = p * t;
  const float e = __builtin_amdgcn_exp2f(-a * (a * 1.4426950408889634f)); // exp(-a^2)
  float erfa = fmaf(-p, e, 1.0f);                 // erf(|z|)
  erfa = copysignf(erfa, z);
  return 0.5f * x * (1.0f + erfa);
}

// write-only half of an exchange
__device__ __forceinline__ void wr8(v2f X[8], v2f Y[8], float4* lds,
                                    int wb, int ws) {
#pragma unroll
  for (int k = 0; k < 8; k++) ST4(wb + ws*k, k);
}

// ---- setup: khp float4 units (re_e, re_o, im_e, im_o), bins in bitrev13 order,
// value = (Kh(f)+1)/L ; each thread computes f in [0,4096] and writes f and L-f (conj)
__global__ void ssm_setup(const float* __restrict__ Lr, const float* __restrict__ Li,
                          const float* __restrict__ Pv, const float* __restrict__ Bv,
                          const float* __restrict__ Cv, const float* __restrict__ Sv,
                          float* __restrict__ khp) {
  const int f = blockIdx.x * blockDim.x + threadIdx.x;
  const int layer = blockIdx.y;
  if (f > LL/2) return;
  const double step = (double)Sv[layer];
  const float* lr = Lr + layer * NSTATE;
  const float* li = Li + layer * NSTATE;
  const float* pp = Pv + layer * NSTATE;
  const float* bb = Bv + layer * NSTATE;
  const float* ct = Cv + layer * NSTATE;
  const double ts = 2.0 / step;

  double Kr[2], Ki[2];
  const int f2[2] = { f, (LL - f) & (LL - 1) };
#pragma unroll 1
  for (int s = 0; s < 2; s++) {
    const double th = -2.0 * PI_D * (double)f2[s] / (double)LL;
    const double co = cos(th), si = sin(th);
    const double pr = 1.0 + co, pim = si;
    const double pd = pr*pr + pim*pim;
    const double rpd = 1.0 / pd;
    const double cr = 2.0*pr*rpd, ci = -2.0*pim*rpd;        // c = 2/(1+Om)
    const double mr = 1.0 - co, mi = -si;
    const double gr = ts*(mr*pr + mi*pim)*rpd;              // g = ts*(1-Om)/(1+Om)
    const double gi = ts*(mi*pr - mr*pim)*rpd;
    double k00r=0,k00i=0,k01r=0,k01i=0,k10r=0,k10i=0,k11r=0,k11i=0;
    for (int n = 0; n < NSTATE; n++) {
      const double dr = gr - (double)lr[n];
      const double di = gi - (double)li[n];
      const double rd = 1.0 / (dr*dr + di*di);
      const double ir = dr*rd, ii = -di*rd;                 // 1/denom
      const double p = (double)pp[n], b = (double)bb[n], c = (double)ct[n];
      double w;
      w = c*b; k00r += w*ir; k00i += w*ii;
      w = c*p; k01r += w*ir; k01i += w*ii;
      w = p*b; k10r += w*ir; k10i += w*ii;
      w = p*p; k11r += w*ir; k11i += w*ii;
    }
    const double ar = k01r*k10r - k01i*k10i;
    const double ai = k01r*k10i + k01i*k10r;
    const double qr = 1.0 + k11r, qi = k11i;
    const double rqd = 1.0 / (qr*qr + qi*qi);
    const double br = (ar*qr + ai*qi)*rqd, bi = (ai*qr - ar*qi)*rqd;
    const double sr = k00r - br, sj = k00i - bi;
    Kr[s] = cr*sr - ci*sj;
    Ki[s] = cr*sj + ci*sr;
  }
  const double hr = 0.5*(Kr[0] + Kr[1]);                    // Hermitian part
  const double hi = 0.5*(Ki[0] - Ki[1]);
  const double invL = 1.0 / (double)LL;
  const float re = (float)((hr + 1.0)*invL);
  const float im = (float)(hi*invL);
  const int i0 = (int)(__brev((unsigned)f) >> 19);
  const int i1 = (int)(__brev((unsigned)f2[1]) >> 19);
  float* kl = khp + layer * (LL * 2);                       // 16384 floats per layer
  kl[(i0 >> 1)*4 + (i0 & 1)]     = re;                      // bin f
  kl[(i0 >> 1)*4 + 2 + (i0 & 1)] = im;
  kl[(i1 >> 1)*4 + (i1 & 1)]     = re;                      // bin L-f = conj
  kl[(i1 >> 1)*4 + 2 + (i1 & 1)] = -im;
}

// ---- fused 4-layer SSM, packed-fp32 layout:
// unit u holds complex elements (2u, 2u+1); X = re pair, Y = im pair.
// __launch_bounds__(512,4): allocator lands at exactly 64 VGPR; (512,8) caps
// at 32 VGPR -> catastrophic scratch spilling. Empirical law: resident
// waves x VGPR ~ 1024/CU (r1: 32x32, r2: 16x64), so at 64 VGPR we get
// 2 blocks/CU regardless of LDS; the 73.7KB buffer is free.
__global__ __launch_bounds__(512, 4) void ssm_fused(const float* __restrict__ uin,
                                                    const float* __restrict__ khp,
                                                    float* __restrict__ uout) {
  __shared__ float4 lds[4607];   // 4096 float4 units (+1 pad per 8) = 73,712 B
  const int t = threadIdx.x;
  const size_t rb = (size_t)blockIdx.x * (2 * LL);
  const v2f* p0 = (const v2f*)(uin + rb);
  const v2f* p1 = (const v2f*)(uin + rb + LL);

  v2f X[8], Y[8];                // unit index t + 512k
#pragma unroll
  for (int k = 0; k < 8; k++) {
    X[k] = p0[t + 512*k];
    Y[k] = p1[t + 512*k];
  }

  v2f e13x, e13y, e10x, e10y, e7x, e7y;
  {
    const float w13 = -(float)(2.0 * PI_D / 8192.0);
    const float w10 = -(float)(2.0 * PI_D / 1024.0);
    const float w7  = -(float)(2.0 * PI_D / 128.0);
    float c0, s0, c1, s1, r;
    r = (float)(2*t);       sincosf(w13*r, &s0, &c0); sincosf(w13*(r+1.0f), &s1, &c1);
    e13x = v2f{c0, c1}; e13y = v2f{s0, s1};
    r = (float)(2*(t&63));  sincosf(w10*r, &s0, &c0); sincosf(w10*(r+1.0f), &s1, &c1);
    e10x = v2f{c0, c1}; e10y = v2f{s0, s1};
    r = (float)(2*(t&7));   sincosf(w7*r, &s0, &c0);  sincosf(w7*(r+1.0f), &s1, &c1);
    e7x = v2f{c0, c1};  e7y = v2f{s0, s1};
  }

  const int m6 = t & 63;
  const int b1 = t + (t >> 3);                  // {t + 512k} units, stride 576 (cross-slice)
  const int b2 = 576*(t >> 6) + m6 + (m6 >> 3); // {512g + m + 64k}, stride 72 (own slice)
  const int b3 = 72*(t >> 3) + (t & 7);         // {64g + s + 8k}, stride 9 (own slice)
  const int b4 = 9*t;                           // {8t + j}, stride 1 (own slice)

  const float4* kb = (const float4*)khp;

#pragma unroll 1
  for (int layer = 0; layer < NLAYERS; layer++) {
    // F1: DIF m=8192,4096,2048 (data in regs)
    dif3p(X, Y, e13x, e13y);
    __syncthreads();                     // WAR vs prev layer's cross-slice I4 reads
    wr8(X, Y, lds, b1, 576);             // cross-slice write
    __syncthreads();                     // RAW
    // F2: m=1024,512,256  (read own slice + compute, fused)
    ld_dif3p(X, Y, lds, b2, 72, e10x, e10y);
    wr8(X, Y, lds, b2, 72);              // own slice, in-wave ordered
    // F3: m=128,64,32
    ld_dif3p(X, Y, lds, b3, 9, e7x, e7y);
    wr8(X, Y, lds, b3, 9);
    // F45 + pointwise (bit-reversed) + I1
    {
      float4 kq[8];
      const float4* kv = kb + (layer << 12) + 8*t;
#pragma unroll
      for (int k = 0; k < 8; k++) kq[k] = kv[k];   // global loads overlap LDS reads
      ld_fwd4p(X, Y, lds, b4);
#pragma unroll
      for (int k = 0; k < 8; k++) {
        v2f kx = {kq[k].x, kq[k].y}, ky = {kq[k].z, kq[k].w};
        v2f nx, ny;
        CMULP(nx, ny, X[k], Y[k], kx, ky);
        X[k] = nx; Y[k] = ny;
      }
      inv4p(X, Y);
    }
    wr8(X, Y, lds, b4, 1);
    // I2: m=32,64,128
    ld_dit3p(X, Y, lds, b3, 9, e7x, e7y);
    wr8(X, Y, lds, b3, 9);
    // I3: m=256,512,1024
    ld_dit3p(X, Y, lds, b2, 72, e10x, e10y);
    wr8(X, Y, lds, b2, 72);              // own slice
    __syncthreads();                     // RAW before cross-slice I4 reads
    // I4: m=2048,4096,8192, then GELU (1/L folded into khp)
    ld_dit3p(X, Y, lds, b1, 576, e13x, e13y);
#pragma unroll
    for (int k = 0; k < 8; k++) {
      X[k].x = gelu_fast(X[k].x); X[k].y = gelu_fast(X[k].y);
      Y[k].x = gelu_fast(Y[k].x); Y[k].y = gelu_fast(Y[k].y);
    }
  }

  v2f* o0 = (v2f*)(uout + rb);
  v2f* o1 = (v2f*)(uout + rb + LL);
#pragma unroll
  for (int k = 0; k < 8; k++) {
    o0[t + 512*k] = X[k];
    o1[t + 512*k] = Y[k];
  }
}

extern "C" void kernel_launch(void* const* d_in, const int* in_sizes, int n_in,
                              void* d_out, int out_size, void* d_ws, size_t ws_size,
                              hipStream_t stream) {
  const float* u  = (const float*)d_in[0];
  const float* Lr = (const float*)d_in[1];
  const float* Li = (const float*)d_in[2];
  const float* P  = (const float*)d_in[3];
  const float* B  = (const float*)d_in[4];
  const float* C  = (const float*)d_in[5];
  const float* S  = (const float*)d_in[6];
  float* khp = (float*)d_ws;  // 4 layers * 16384 floats = 256 KB

  hipLaunchKernelGGL(ssm_setup, dim3((LL/2 + 256) / 256, NLAYERS), dim3(256), 0, stream,
                     Lr, Li, P, B, C, S, khp);
  hipLaunchKernelGGL(ssm_fused, dim3(4096/2), dim3(512), 0, stream,
                     u, khp, (float*)d_out);
}

// Round 8
// 232.157 us; speedup vs baseline: 1.0444x; 1.0263x over previous
//
#include <hip/hip_runtime.h>
#include <math.h>

#define LL 8192
#define NLAYERS 4
#define NSTATE 64
#define SQ2H 0.70710678118654752f
#define PI_D 3.14159265358979323846

typedef float v2f __attribute__((ext_vector_type(2)));

// packed complex helpers: (X,Y) = (re-pair, im-pair), twiddle (tx,ty)
// NOTE: plain C++ v2f arithmetic. Round 6 proved v_pk_*_f32 is RATE-NEUTRAL
// on gfx950 (fp32 peak == scalar issue rate) and asm packing hurt scheduling.
#define CMULP(rx, ry, zx, zy, tx, ty) { rx = (zx)*(tx) - (zy)*(ty); ry = (zx)*(ty) + (zy)*(tx); }
#define CMULCP(rx, ry, zx, zy, tx, ty) { rx = (zx)*(tx) + (zy)*(ty); ry = (zy)*(tx) - (zx)*(ty); }

#define LD4(idx, k) { float4 q = lds[idx]; X[k] = v2f{q.x, q.y}; Y[k] = v2f{q.z, q.w}; }
#define ST4(idx, k) lds[idx] = make_float4(X[k].x, X[k].y, Y[k].x, Y[k].y)

// 3 forward DIF stages (sizes 8S,4S,2S), data in registers, no store (F1:
// the cross-slice store must sit after the WAR barrier).
__device__ __forceinline__ void dif3p(v2f X[8], v2f Y[8], v2f t1x, v2f t1y) {
  v2f t2x = t1x*t1x - t1y*t1y, t2y = 2.0f*(t1x*t1y);
  v2f t4x = t2x*t2x - t2y*t2y, t4y = 2.0f*(t2x*t2y);
#pragma unroll
  for (int k = 0; k < 4; k++) {          // m=8S: (k,k+4), tw = C8[k]*t1
    v2f ax = X[k], ay = Y[k], bx = X[k+4], by = Y[k+4];
    X[k] = ax + bx; Y[k] = ay + by;
    v2f dx = ax - bx, dy = ay - by, ex, ey;
    if (k == 0)      { ex = dx; ey = dy; }
    else if (k == 1) { ex = (dx + dy) * SQ2H; ey = (dy - dx) * SQ2H; }
    else if (k == 2) { ex = dy; ey = -dx; }
    else             { ex = (dy - dx) * SQ2H; ey = -((dx + dy) * SQ2H); }
    CMULP(X[k+4], Y[k+4], ex, ey, t1x, t1y);
  }
#pragma unroll
  for (int h = 0; h < 8; h += 4)         // m=4S: (k,k+2), tw = t2*{1,-i}
#pragma unroll
    for (int l = 0; l < 2; l++) {
      int k = h + l;
      v2f ax = X[k], ay = Y[k], bx = X[k+2], by = Y[k+2];
      X[k] = ax + bx; Y[k] = ay + by;
      v2f dx = ax - bx, dy = ay - by, ex, ey;
      CMULP(ex, ey, dx, dy, t2x, t2y);
      if (l == 0) { X[k+2] = ex; Y[k+2] = ey; }
      else        { X[k+2] = ey; Y[k+2] = -ex; }   // * -i
    }
#pragma unroll
  for (int k = 0; k < 8; k += 2) {       // m=2S: (k,k+1), tw = t4
    v2f ax = X[k], ay = Y[k], bx = X[k+1], by = Y[k+1];
    X[k] = ax + bx; Y[k] = ay + by;
    v2f dx = ax - bx, dy = ay - by;
    CMULP(X[k+1], Y[k+1], dx, dy, t4x, t4y);
  }
}

// Fused LDS-read + 3 forward DIF stages + fused store (F2/F3): reads issue in
// butterfly-pair order so compute starts after 2 LDS returns; each last-stage
// pair is STORED the moment it's computed (in-wave DS ordering makes
// read-then-write of the same wave-private slots safe), so the next phase's
// reads can issue ~a stage earlier than a trailing 8-store burst would allow.
__device__ __forceinline__ void ld_dif3p_st(v2f X[8], v2f Y[8], float4* lds,
                                            int rb, int rs, v2f t1x, v2f t1y) {
  v2f t2x = t1x*t1x - t1y*t1y, t2y = 2.0f*(t1x*t1y);
  v2f t4x = t2x*t2x - t2y*t2y, t4y = 2.0f*(t2x*t2y);
#pragma unroll
  for (int k = 0; k < 4; k++) {          // m=8S: (k,k+4), tw = C8[k]*t1
    LD4(rb + rs*k, k);
    LD4(rb + rs*(k+4), k+4);
    v2f ax = X[k], ay = Y[k], bx = X[k+4], by = Y[k+4];
    X[k] = ax + bx; Y[k] = ay + by;
    v2f dx = ax - bx, dy = ay - by, ex, ey;
    if (k == 0)      { ex = dx; ey = dy; }
    else if (k == 1) { ex = (dx + dy) * SQ2H; ey = (dy - dx) * SQ2H; }
    else if (k == 2) { ex = dy; ey = -dx; }
    else             { ex = (dy - dx) * SQ2H; ey = -((dx + dy) * SQ2H); }
    CMULP(X[k+4], Y[k+4], ex, ey, t1x, t1y);
  }
#pragma unroll
  for (int h = 0; h < 8; h += 4)         // m=4S
#pragma unroll
    for (int l = 0; l < 2; l++) {
      int k = h + l;
      v2f ax = X[k], ay = Y[k], bx = X[k+2], by = Y[k+2];
      X[k] = ax + bx; Y[k] = ay + by;
      v2f dx = ax - bx, dy = ay - by, ex, ey;
      CMULP(ex, ey, dx, dy, t2x, t2y);
      if (l == 0) { X[k+2] = ex; Y[k+2] = ey; }
      else        { X[k+2] = ey; Y[k+2] = -ex; }
    }
#pragma unroll
  for (int k = 0; k < 8; k += 2) {       // m=2S + store-as-computed
    v2f ax = X[k], ay = Y[k], bx = X[k+1], by = Y[k+1];
    X[k] = ax + bx; Y[k] = ay + by;
    v2f dx = ax - bx, dy = ay - by;
    CMULP(X[k+1], Y[k+1], dx, dy, t4x, t4y);
    ST4(rb + rs*k, k);
    ST4(rb + rs*(k+1), k+1);
  }
}

// Fused LDS-read + 3 inverse DIT stages (pure, for I4: no store after).
__device__ __forceinline__ void ld_dit3p(v2f X[8], v2f Y[8], const float4* lds,
                                         int rb, int rs, v2f t1x, v2f t1y) {
  v2f t2x = t1x*t1x - t1y*t1y, t2y = 2.0f*(t1x*t1y);
  v2f t4x = t2x*t2x - t2y*t2y, t4y = 2.0f*(t2x*t2y);
#pragma unroll
  for (int k = 0; k < 8; k += 2) {       // m1: (k,k+1), b *= conj(t4)
    LD4(rb + rs*k, k);
    LD4(rb + rs*(k+1), k+1);
    v2f bx, by;
    CMULCP(bx, by, X[k+1], Y[k+1], t4x, t4y);
    v2f ax = X[k], ay = Y[k];
    X[k] = ax + bx;   Y[k] = ay + by;
    X[k+1] = ax - bx; Y[k+1] = ay - by;
  }
#pragma unroll
  for (int h = 0; h < 8; h += 4)         // 2m1: (k,k+2), b *= conj(t2)*{1,+i}
#pragma unroll
    for (int l = 0; l < 2; l++) {
      int k = h + l;
      v2f bx, by;
      CMULCP(bx, by, X[k+2], Y[k+2], t2x, t2y);
      if (l == 1) { v2f tm = bx; bx = -by; by = tm; }  // * +i
      v2f ax = X[k], ay = Y[k];
      X[k] = ax + bx;   Y[k] = ay + by;
      X[k+2] = ax - bx; Y[k+2] = ay - by;
    }
#pragma unroll
  for (int k = 0; k < 4; k++) {          // 4m1: (k,k+4), b = conj(C8[k])*conj(t1)*b
    v2f cx, cy;
    CMULCP(cx, cy, X[k+4], Y[k+4], t1x, t1y);
    v2f bx, by;
    if (k == 0)      { bx = cx; by = cy; }
    else if (k == 1) { bx = (cx - cy) * SQ2H; by = (cx + cy) * SQ2H; }
    else if (k == 2) { bx = -cy; by = cx; }
    else             { bx = -((cx + cy) * SQ2H); by = (cx - cy) * SQ2H; }
    v2f ax = X[k], ay = Y[k];
    X[k] = ax + bx;   Y[k] = ay + by;
    X[k+4] = ax - bx; Y[k+4] = ay - by;
  }
}

// Fused read + 3 inverse DIT stages + fused store (I2/I3).
__device__ __forceinline__ void ld_dit3p_st(v2f X[8], v2f Y[8], float4* lds,
                                            int rb, int rs, v2f t1x, v2f t1y) {
  v2f t2x = t1x*t1x - t1y*t1y, t2y = 2.0f*(t1x*t1y);
  v2f t4x = t2x*t2x - t2y*t2y, t4y = 2.0f*(t2x*t2y);
#pragma unroll
  for (int k = 0; k < 8; k += 2) {       // m1: (k,k+1), b *= conj(t4)
    LD4(rb + rs*k, k);
    LD4(rb + rs*(k+1), k+1);
    v2f bx, by;
    CMULCP(bx, by, X[k+1], Y[k+1], t4x, t4y);
    v2f ax = X[k], ay = Y[k];
    X[k] = ax + bx;   Y[k] = ay + by;
    X[k+1] = ax - bx; Y[k+1] = ay - by;
  }
#pragma unroll
  for (int h = 0; h < 8; h += 4)         // 2m1
#pragma unroll
    for (int l = 0; l < 2; l++) {
      int k = h + l;
      v2f bx, by;
      CMULCP(bx, by, X[k+2], Y[k+2], t2x, t2y);
      if (l == 1) { v2f tm = bx; bx = -by; by = tm; }
      v2f ax = X[k], ay = Y[k];
      X[k] = ax + bx;   Y[k] = ay + by;
      X[k+2] = ax - bx; Y[k+2] = ay - by;
    }
#pragma unroll
  for (int k = 0; k < 4; k++) {          // 4m1 + store-as-computed
    v2f cx, cy;
    CMULCP(cx, cy, X[k+4], Y[k+4], t1x, t1y);
    v2f bx, by;
    if (k == 0)      { bx = cx; by = cy; }
    else if (k == 1) { bx = (cx - cy) * SQ2H; by = (cx + cy) * SQ2H; }
    else if (k == 2) { bx = -cy; by = cx; }
    else             { bx = -((cx + cy) * SQ2H); by = (cx - cy) * SQ2H; }
    v2f ax = X[k], ay = Y[k];
    X[k]   = ax + bx; Y[k]   = ay + by;
    X[k+4] = ax - bx; Y[k+4] = ay - by;
    ST4(rb + rs*k, k);
    ST4(rb + rs*(k+4), k+4);
  }
}

// Fused LDS-read (stride 1) + forward stages m=16,8,4,2
__device__ __forceinline__ void ld_fwd4p(v2f X[8], v2f Y[8], const float4* lds,
                                         int rb) {
  const float c16[8] = {1.f, 0.92387953f, 0.70710678f, 0.38268343f,
                        0.f, -0.38268343f, -0.70710678f, -0.92387953f};
  const float s16[8] = {0.f, -0.38268343f, -0.70710678f, -0.92387953f,
                        -1.f, -0.92387953f, -0.70710678f, -0.38268343f};
#pragma unroll
  for (int k = 0; k < 4; k++) {          // m=16: (k,k+4), tw = W16^{2k+lane}
    LD4(rb + k, k);
    LD4(rb + k + 4, k+4);
    v2f tx = {c16[2*k], c16[2*k+1]}, ty = {s16[2*k], s16[2*k+1]};
    v2f ax = X[k], ay = Y[k], bx = X[k+4], by = Y[k+4];
    X[k] = ax + bx; Y[k] = ay + by;
    v2f dx = ax - bx, dy = ay - by;
    CMULP(X[k+4], Y[k+4], dx, dy, tx, ty);
  }
#pragma unroll
  for (int h = 0; h < 8; h += 4)         // m=8: (k,k+2), tw = W8^{2l+lane}
#pragma unroll
    for (int l = 0; l < 2; l++) {
      int k = h + l;
      v2f tx = (l == 0) ? v2f{1.f, SQ2H} : v2f{0.f, -SQ2H};
      v2f ty = (l == 0) ? v2f{0.f, -SQ2H} : v2f{-1.f, -SQ2H};
      v2f ax = X[k], ay = Y[k], bx = X[k+2], by = Y[k+2];
      X[k] = ax + bx; Y[k] = ay + by;
      v2f dx = ax - bx, dy = ay - by;
      CMULP(X[k+2], Y[k+2], dx, dy, tx, ty);
    }
#pragma unroll
  for (int k = 0; k < 8; k += 2) {       // m=4: (k,k+1), tw = {1,-i} per lane
    v2f ax = X[k], ay = Y[k], bx = X[k+1], by = Y[k+1];
    X[k] = ax + bx; Y[k] = ay + by;
    v2f dx = ax - bx, dy = ay - by;
    X[k+1] = v2f{dx.x, dy.y};
    Y[k+1] = v2f{dy.x, -dx.y};
  }
#pragma unroll
  for (int u = 0; u < 8; u++) {          // m=2: cross-lane
    v2f x = X[u], y = Y[u];
    X[u] = v2f{x.x + x.y, x.x - x.y};
    Y[u] = v2f{y.x + y.y, y.x - y.y};
  }
}

// inverse stages m=2,4,8,16 (data in regs) + fused store of the final stage
__device__ __forceinline__ void inv4p_st(v2f X[8], v2f Y[8], float4* lds,
                                         int wb) {
  const float c16[8] = {1.f, 0.92387953f, 0.70710678f, 0.38268343f,
                        0.f, -0.38268343f, -0.70710678f, -0.92387953f};
  const float s16[8] = {0.f, -0.38268343f, -0.70710678f, -0.92387953f,
                        -1.f, -0.92387953f, -0.70710678f, -0.38268343f};
#pragma unroll
  for (int u = 0; u < 8; u++) {          // m=2: cross-lane
    v2f x = X[u], y = Y[u];
    X[u] = v2f{x.x + x.y, x.x - x.y};
    Y[u] = v2f{y.x + y.y, y.x - y.y};
  }
#pragma unroll
  for (int k = 0; k < 8; k += 2) {       // m=4: (k,k+1), b *= {1,+i} per lane
    v2f bx0 = X[k+1], by0 = Y[k+1];
    v2f bx = v2f{bx0.x, -by0.y};
    v2f by = v2f{by0.x, bx0.y};
    v2f ax = X[k], ay = Y[k];
    X[k] = ax + bx;   Y[k] = ay + by;
    X[k+1] = ax - bx; Y[k+1] = ay - by;
  }
#pragma unroll
  for (int h = 0; h < 8; h += 4)         // m=8: (k,k+2), b *= conj(W8^{2l+lane})
#pragma unroll
    for (int l = 0; l < 2; l++) {
      int k = h + l;
      v2f tx = (l == 0) ? v2f{1.f, SQ2H} : v2f{0.f, -SQ2H};
      v2f ty = (l == 0) ? v2f{0.f, -SQ2H} : v2f{-1.f, -SQ2H};
      v2f bx, by;
      CMULCP(bx, by, X[k+2], Y[k+2], tx, ty);
      v2f ax = X[k], ay = Y[k];
      X[k] = ax + bx;   Y[k] = ay + by;
      X[k+2] = ax - bx; Y[k+2] = ay - by;
    }
#pragma unroll
  for (int k = 0; k < 4; k++) {          // m=16: (k,k+4) + store-as-computed
    v2f tx = {c16[2*k], c16[2*k+1]}, ty = {s16[2*k], s16[2*k+1]};
    v2f bx, by;
    CMULCP(bx, by, X[k+4], Y[k+4], tx, ty);
    v2f ax = X[k], ay = Y[k];
    X[k]   = ax + bx; Y[k]   = ay + by;
    X[k+4] = ax - bx; Y[k+4] = ay - by;
    ST4(wb + k, k);
    ST4(wb + k + 4, k+4);
  }
}

// Branch-free GELU: erf via Abramowitz-Stegun 7.1.25 (3-term, |err| <= 2.5e-5
// -- still 2.5 decades below the ~7.8e-3 fp32 FFT noise floor; the 7.1.26
// 5-term version's 1.5e-7 was overkill). ~12 VALU, zero divergence, no
// global table fetches (libm erff's tables cost 85MB of FETCH, round 5).
__device__ __forceinline__ float gelu_fast(float x) {
  const float a = fabsf(x) * 0.70710678118654752f;     // |x|/sqrt(2)
  const float t = __builtin_amdgcn_rcpf(fmaf(0.47047f, a, 1.0f));
  float p = fmaf(0.7478556f, t, -0.0958798f);
  p = fmaf(p, t, 0.3480242f);
  p = p * t;
  const float e = __builtin_amdgcn_exp2f(-a * (a * 1.4426950408889634f)); // exp(-a^2)
  float erfa = fmaf(-p, e, 1.0f);                      // erf(|x|/sqrt2)
  erfa = copysignf(erfa, x);
  const float hx = 0.5f * x;
  return fmaf(hx, erfa, hx);                           // 0.5x(1+erf)
}

// cross-slice write burst (F1 only: must follow the WAR barrier)
__device__ __forceinline__ void wr8(v2f X[8], v2f Y[8], float4* lds,
                                    int wb, int ws) {
#pragma unroll
  for (int k = 0; k < 8; k++) ST4(wb + ws*k, k);
}

// ---- setup: khp float4 units (re_e, re_o, im_e, im_o), bins in bitrev13 order,
// value = (Kh(f)+1)/L ; each thread computes f in [0,4096] and writes f and L-f (conj)
__global__ void ssm_setup(const float* __restrict__ Lr, const float* __restrict__ Li,
                          const float* __restrict__ Pv, const float* __restrict__ Bv,
                          const float* __restrict__ Cv, const float* __restrict__ Sv,
                          float* __restrict__ khp) {
  const int f = blockIdx.x * blockDim.x + threadIdx.x;
  const int layer = blockIdx.y;
  if (f > LL/2) return;
  const double step = (double)Sv[layer];
  const float* lr = Lr + layer * NSTATE;
  const float* li = Li + layer * NSTATE;
  const float* pp = Pv + layer * NSTATE;
  const float* bb = Bv + layer * NSTATE;
  const float* ct = Cv + layer * NSTATE;
  const double ts = 2.0 / step;

  double Kr[2], Ki[2];
  const int f2[2] = { f, (LL - f) & (LL - 1) };
#pragma unroll 1
  for (int s = 0; s < 2; s++) {
    const double th = -2.0 * PI_D * (double)f2[s] / (double)LL;
    const double co = cos(th), si = sin(th);
    const double pr = 1.0 + co, pim = si;
    const double pd = pr*pr + pim*pim;
    const double rpd = 1.0 / pd;
    const double cr = 2.0*pr*rpd, ci = -2.0*pim*rpd;        // c = 2/(1+Om)
    const double mr = 1.0 - co, mi = -si;
    const double gr = ts*(mr*pr + mi*pim)*rpd;              // g = ts*(1-Om)/(1+Om)
    const double gi = ts*(mi*pr - mr*pim)*rpd;
    double k00r=0,k00i=0,k01r=0,k01i=0,k10r=0,k10i=0,k11r=0,k11i=0;
    for (int n = 0; n < NSTATE; n++) {
      const double dr = gr - (double)lr[n];
      const double di = gi - (double)li[n];
      const double rd = 1.0 / (dr*dr + di*di);
      const double ir = dr*rd, ii = -di*rd;                 // 1/denom
      const double p = (double)pp[n], b = (double)bb[n], c = (double)ct[n];
      double w;
      w = c*b; k00r += w*ir; k00i += w*ii;
      w = c*p; k01r += w*ir; k01i += w*ii;
      w = p*b; k10r += w*ir; k10i += w*ii;
      w = p*p; k11r += w*ir; k11i += w*ii;
    }
    const double ar = k01r*k10r - k01i*k10i;
    const double ai = k01r*k10i + k01i*k10r;
    const double qr = 1.0 + k11r, qi = k11i;
    const double rqd = 1.0 / (qr*qr + qi*qi);
    const double br = (ar*qr + ai*qi)*rqd, bi = (ai*qr - ar*qi)*rqd;
    const double sr = k00r - br, sj = k00i - bi;
    Kr[s] = cr*sr - ci*sj;
    Ki[s] = cr*sj + ci*sr;
  }
  const double hr = 0.5*(Kr[0] + Kr[1]);                    // Hermitian part
  const double hi = 0.5*(Ki[0] - Ki[1]);
  const double invL = 1.0 / (double)LL;
  const float re = (float)((hr + 1.0)*invL);
  const float im = (float)(hi*invL);
  const int i0 = (int)(__brev((unsigned)f) >> 19);
  const int i1 = (int)(__brev((unsigned)f2[1]) >> 19);
  float* kl = khp + layer * (LL * 2);                       // 16384 floats per layer
  kl[(i0 >> 1)*4 + (i0 & 1)]     = re;                      // bin f
  kl[(i0 >> 1)*4 + 2 + (i0 & 1)] = im;
  kl[(i1 >> 1)*4 + (i1 & 1)]     = re;                      // bin L-f = conj
  kl[(i1 >> 1)*4 + 2 + (i1 & 1)] = -im;
}

// ---- fused 4-layer SSM, packed-fp32 layout:
// unit u holds complex elements (2u, 2u+1); X = re pair, Y = im pair.
// __launch_bounds__(512,4): allocator lands at exactly 64 VGPR; (512,8) caps
// at 32 VGPR -> catastrophic scratch spilling. Empirical law: resident
// waves x VGPR ~ 1024/CU (r1: 32x32, r2: 16x64), so at 64 VGPR we get
// 2 blocks/CU regardless of LDS; the 73.7KB buffer is free.
__global__ __launch_bounds__(512, 4) void ssm_fused(const float* __restrict__ uin,
                                                    const float* __restrict__ khp,
                                                    float* __restrict__ uout) {
  __shared__ float4 lds[4607];   // 4096 float4 units (+1 pad per 8) = 73,712 B
  const int t = threadIdx.x;
  const size_t rb = (size_t)blockIdx.x * (2 * LL);
  const v2f* p0 = (const v2f*)(uin + rb);
  const v2f* p1 = (const v2f*)(uin + rb + LL);

  v2f X[8], Y[8];                // unit index t + 512k
#pragma unroll
  for (int k = 0; k < 8; k++) {
    X[k] = p0[t + 512*k];
    Y[k] = p1[t + 512*k];
  }

  v2f e13x, e13y, e10x, e10y, e7x, e7y;
  {
    const float w13 = -(float)(2.0 * PI_D / 8192.0);
    const float w10 = -(float)(2.0 * PI_D / 1024.0);
    const float w7  = -(float)(2.0 * PI_D / 128.0);
    float c0, s0, c1, s1, r;
    r = (float)(2*t);       sincosf(w13*r, &s0, &c0); sincosf(w13*(r+1.0f), &s1, &c1);
    e13x = v2f{c0, c1}; e13y = v2f{s0, s1};
    r = (float)(2*(t&63));  sincosf(w10*r, &s0, &c0); sincosf(w10*(r+1.0f), &s1, &c1);
    e10x = v2f{c0, c1}; e10y = v2f{s0, s1};
    r = (float)(2*(t&7));   sincosf(w7*r, &s0, &c0);  sincosf(w7*(r+1.0f), &s1, &c1);
    e7x = v2f{c0, c1};  e7y = v2f{s0, s1};
  }

  const int m6 = t & 63;
  const int b1 = t + (t >> 3);                  // {t + 512k} units, stride 576 (cross-slice)
  const int b2 = 576*(t >> 6) + m6 + (m6 >> 3); // {512g + m + 64k}, stride 72 (own slice)
  const int b3 = 72*(t >> 3) + (t & 7);         // {64g + s + 8k}, stride 9 (own slice)
  const int b4 = 9*t;                           // {8t + j}, stride 1 (own slice)

  const float4* kb = (const float4*)khp;

#pragma unroll 1
  for (int layer = 0; layer < NLAYERS; layer++) {
    // F1: DIF m=8192,4096,2048 (data in regs)
    dif3p(X, Y, e13x, e13y);
    __syncthreads();                     // WAR vs prev layer's cross-slice I4 reads
    wr8(X, Y, lds, b1, 576);             // cross-slice write
    __syncthreads();                     // RAW
    // F2: m=1024,512,256  (read + compute + store fused, own slice)
    ld_dif3p_st(X, Y, lds, b2, 72, e10x, e10y);
    // F3: m=128,64,32
    ld_dif3p_st(X, Y, lds, b3, 9, e7x, e7y);
    // F45 + pointwise (bit-reversed) + I1 (+ fused store b4)
    {
      float4 kq[8];
      const float4* kv = kb + (layer << 12) + 8*t;
#pragma unroll
      for (int k = 0; k < 8; k++) kq[k] = kv[k];   // global loads overlap LDS reads
      ld_fwd4p(X, Y, lds, b4);
#pragma unroll
      for (int k = 0; k < 8; k++) {
        v2f kx = {kq[k].x, kq[k].y}, ky = {kq[k].z, kq[k].w};
        v2f nx, ny;
        CMULP(nx, ny, X[k], Y[k], kx, ky);
        X[k] = nx; Y[k] = ny;
      }
      inv4p_st(X, Y, lds, b4);
    }
    // I2: m=32,64,128
    ld_dit3p_st(X, Y, lds, b3, 9, e7x, e7y);
    // I3: m=256,512,1024
    ld_dit3p_st(X, Y, lds, b2, 72, e10x, e10y);
    __syncthreads();                     // RAW before cross-slice I4 reads
    // I4: m=2048,4096,8192, then GELU (1/L folded into khp)
    ld_dit3p(X, Y, lds, b1, 576, e13x, e13y);
#pragma unroll
    for (int k = 0; k < 8; k++) {
      X[k].x = gelu_fast(X[k].x); X[k].y = gelu_fast(X[k].y);
      Y[k].x = gelu_fast(Y[k].x); Y[k].y = gelu_fast(Y[k].y);
    }
  }

  v2f* o0 = (v2f*)(uout + rb);
  v2f* o1 = (v2f*)(uout + rb + LL);
#pragma unroll
  for (int k = 0; k < 8; k++) {
    o0[t + 512*k] = X[k];
    o1[t + 512*k] = Y[k];
  }
}

extern "C" void kernel_launch(void* const* d_in, const int* in_sizes, int n_in,
                              void* d_out, int out_size, void* d_ws, size_t ws_size,
                              hipStream_t stream) {
  const float* u  = (const float*)d_in[0];
  const float* Lr = (const float*)d_in[1];
  const float* Li = (const float*)d_in[2];
  const float* P  = (const float*)d_in[3];
  const float* B  = (const float*)d_in[4];
  const float* C  = (const float*)d_in[5];
  const float* S  = (const float*)d_in[6];
  float* khp = (float*)d_ws;  // 4 layers * 16384 floats = 256 KB

  hipLaunchKernelGGL(ssm_setup, dim3((LL/2 + 256) / 256, NLAYERS), dim3(256), 0, stream,
                     Lr, Li, P, B, C, S, khp);
  hipLaunchKernelGGL(ssm_fused, dim3(4096/2), dim3(512), 0, stream,
                     u, khp, (float*)d_out);
}